// Round 6
// baseline (253.975 us; speedup 1.0000x reference)
//
#include <hip/hip_runtime.h>
#include <hip/hip_bf16.h>

// GCN 2-layer encoder. R6: fuse adjacency build into GEMM1 (overlap scattered
// write-drain with MFMA), fuse GEMM2 into gather1 via LDS tile; dinv applied
// per-source inside gathers so GEMMs have no dependency on degrees.
// out[d] = dinv[d] * sum_{s in N(d) U {d}} dinv[s]*h[s] + b,  h = in @ W
// dinv = rsqrt(1 + indeg).

constexpr int FIN = 128;
constexpr int HID = 128;
constexpr int FOUT = 64;
constexpr int CAP = 48;          // adjacency slots per node (Poisson(16) max ~36)
constexpr int OVF_MAX = 196608;  // overflow pairs capacity

typedef __attribute__((ext_vector_type(8))) short s16x8;
typedef __attribute__((ext_vector_type(4))) float f32x4;

static __device__ __forceinline__ float bf2f(__hip_bfloat16 v) { return __bfloat162float(v); }
static __device__ __forceinline__ float lo2f(unsigned u) { union { unsigned i; float f; } c; c.i = u << 16; return c.f; }
static __device__ __forceinline__ float hi2f(unsigned u) { union { unsigned i; float f; } c; c.i = u & 0xffff0000u; return c.f; }
static __device__ __forceinline__ unsigned short f2bfu(float f) {
    __hip_bfloat16 h = __float2bfloat16(f);
    union { __hip_bfloat16 h; unsigned short u; } c; c.h = h; return c.u;
}
static __device__ __forceinline__ unsigned pack2(float a, float b) {
    return (unsigned)f2bfu(a) | ((unsigned)f2bfu(b) << 16);
}
static __device__ __forceinline__ void acc_fma(float* acc, uint4 v, float w) {
    acc[0] += w * lo2f(v.x); acc[1] += w * hi2f(v.x);
    acc[2] += w * lo2f(v.y); acc[3] += w * hi2f(v.y);
    acc[4] += w * lo2f(v.z); acc[5] += w * hi2f(v.z);
    acc[6] += w * lo2f(v.w); acc[7] += w * hi2f(v.w);
}

// flags[0]=1 if floats are f32 in memory (else bf16); flags[1]=1 if edge_index int64
__global__ __launch_bounds__(256) void k_detect(const unsigned* __restrict__ xw,
                                                const int* __restrict__ eiw,
                                                int E, int* __restrict__ flags) {
    __shared__ int s_bf16like, s_oddnz;
    if (threadIdx.x == 0) { s_bf16like = 0; s_oddnz = 0; }
    __syncthreads();
    int cnt = 0;
    for (int i = threadIdx.x; i < 4096; i += 256) {
        unsigned ex = ((xw[i] & 0xffffu) >> 7) & 0xffu;
        if (ex >= 117u && ex <= 130u) cnt++;
    }
    atomicAdd(&s_bf16like, cnt);
    int nz = 0;
    for (int i = threadIdx.x; i < 2048; i += 256)
        if (eiw[2 * i + 1] != 0) nz++;
    atomicAdd(&s_oddnz, nz);
    __syncthreads();
    if (threadIdx.x == 0) {
        flags[0] = (s_bf16like < 2048) ? 1 : 0;
        flags[1] = (s_oddnz == 0) ? 1 : 0;
    }
}

// Fused: adjacency build (scattered, write-drain bound) + GEMM1 (MFMA bound).
// g[row,:] = bf16( X[row,:128] @ W1[:128,:128] )   -- UNscaled by dinv.
__global__ __launch_bounds__(256) void k_fused1(const void* __restrict__ Xp,
                                                const void* __restrict__ Wp,
                                                const int* __restrict__ ei, int E, int N,
                                                int* __restrict__ cnt,
                                                int* __restrict__ slots,
                                                int* __restrict__ ovf,
                                                int* __restrict__ ovfcnt,
                                                __hip_bfloat16* __restrict__ G,
                                                const int* __restrict__ flags) {
    __shared__ __align__(16) short Wt[128 * 136];   // W1^T bf16, pad 128->136
    const bool f32m = flags[0] != 0;
    const int tid = threadIdx.x;
    // stage W1^T (loads issue; latency hidden under edge phase)
    for (int i = tid; i < 128 * 128; i += 256) {
        int k = i >> 7, n = i & 127;
        float wv = f32m ? ((const float*)Wp)[(long)k * 128 + n]
                        : bf2f(((const __hip_bfloat16*)Wp)[(long)k * 128 + n]);
        Wt[n * 136 + k] = (short)f2bfu(wv);
    }
    // edge phase: grid-stride over edge list, scattered slot writes
    const bool i64 = flags[1] != 0;
    const long stride = (long)gridDim.x * 256;
    for (long i = (long)blockIdx.x * 256 + tid; i < E; i += stride) {
        int s, d;
        if (i64) { s = ei[2 * i]; d = ei[2 * (long)E + 2 * i]; }
        else     { s = ei[i];     d = ei[(long)E + i]; }
        if ((unsigned)s >= (unsigned)N || (unsigned)d >= (unsigned)N) continue;
        int pos = atomicAdd(&cnt[d], 1);
        if (pos < CAP) {
            slots[(long)d * CAP + pos] = s;
        } else {
            int op = atomicAdd(ovfcnt, 1);
            if (op < OVF_MAX) { ovf[2 * op] = d; ovf[2 * op + 1] = s; }
        }
    }
    __syncthreads();
    // GEMM phase
    const int w = tid >> 6, lane = tid & 63;
    const int m = lane & 15, quad = lane >> 4;
    const int rowA = blockIdx.x * 64 + w * 16 + m;
    const int rowc = rowA < N ? rowA : N - 1;
    const bool xf32 = f32m;
    s16x8 afr[4];
#pragma unroll
    for (int kc = 0; kc < 4; ++kc) {
        const int k0 = kc * 32 + quad * 8;
        if (!xf32) {
            afr[kc] = *(const s16x8*)((const __hip_bfloat16*)Xp + (long)rowc * 128 + k0);
        } else {
            const float* p = (const float*)Xp + (long)rowc * 128 + k0;
            s16x8 t;
#pragma unroll
            for (int j = 0; j < 8; ++j) t[j] = (short)f2bfu(p[j]);
            afr[kc] = t;
        }
    }
    const int rbase = blockIdx.x * 64 + w * 16 + quad * 4;
#pragma unroll
    for (int ct = 0; ct < 8; ++ct) {
        f32x4 acc = {0.f, 0.f, 0.f, 0.f};
#pragma unroll
        for (int kc = 0; kc < 4; ++kc) {
            s16x8 bfr = *(const s16x8*)&Wt[(ct * 16 + m) * 136 + kc * 32 + quad * 8];
            acc = __builtin_amdgcn_mfma_f32_16x16x32_bf16(afr[kc], bfr, acc, 0, 0, 0);
        }
#pragma unroll
        for (int r = 0; r < 4; ++r) {
            int rr = rbase + r;
            if (rr < N) G[(long)rr * 128 + ct * 16 + m] = __float2bfloat16(acc[r]);
        }
    }
}

__global__ __launch_bounds__(256) void k_dinv(const int* __restrict__ cnt,
                                              float* __restrict__ dinv, int N) {
    int i = blockIdx.x * blockDim.x + threadIdx.x;
    if (i < N) dinv[i] = rsqrtf((float)(cnt[i] + 1));  // +1 self loop
}

// Fused gather1 + GEMM2: per block, 16 nodes.
// h1[n,:] = relu( dinv[n]*(sum_s dinv[s]*g[s,:]) + b1 )   (LDS bf16 tile)
// g2[n,:64] = bf16( h1[n,:] @ W2[:128,:64] )              (UNscaled)
__global__ __launch_bounds__(256) void k_gg(const __hip_bfloat16* __restrict__ G,
                                            const int* __restrict__ cnt,
                                            const int* __restrict__ slots,
                                            const int* __restrict__ ovf,
                                            const int* __restrict__ ovfcnt,
                                            const float* __restrict__ dinv,
                                            const void* __restrict__ b1,
                                            const void* __restrict__ W2,
                                            __hip_bfloat16* __restrict__ G2,
                                            const int* __restrict__ flags, int N) {
    __shared__ __align__(16) short Wt[64 * 136];    // W2^T bf16 (17.4 KB)
    __shared__ __align__(16) short Hs[16 * 136];    // h1 tile bf16 (4.4 KB)
    __shared__ float b1s[128];
    const bool f32m = flags[0] != 0;
    const int tid = threadIdx.x;
    for (int i = tid; i < 128 * 64; i += 256) {
        int k = i >> 6, n = i & 63;
        float wv = f32m ? ((const float*)W2)[(long)k * 64 + n]
                        : bf2f(((const __hip_bfloat16*)W2)[(long)k * 64 + n]);
        Wt[n * 136 + k] = (short)f2bfu(wv);
    }
    if (tid < 128)
        b1s[tid] = f32m ? ((const float*)b1)[tid] : bf2f(((const __hip_bfloat16*)b1)[tid]);

    // ---- phase 1: gather (16 lanes per node, 8 cols each) ----
    const int grp = tid >> 4, lane = tid & 15;
    const int node = blockIdx.x * 16 + grp;
    uint4 hv = {0, 0, 0, 0};
    if (node < N) {
        const float wself = dinv[node];
        float acc[8] = {0, 0, 0, 0, 0, 0, 0, 0};
        acc_fma(acc, ((const uint4*)(G + (long)node * 128))[lane], wself);  // self loop
        const int cd = cnt[node];
        const int m = cd < CAP ? cd : CAP;
        const int* sl = slots + (long)node * CAP;
        int i = 0;
        for (; i + 1 < m; i += 2) {
            int s0 = sl[i], s1 = sl[i + 1];
            float w0 = dinv[s0], w1 = dinv[s1];
            uint4 v0 = ((const uint4*)(G + (long)s0 * 128))[lane];
            uint4 v1 = ((const uint4*)(G + (long)s1 * 128))[lane];
            acc_fma(acc, v0, w0); acc_fma(acc, v1, w1);
        }
        if (i < m) { int s0 = sl[i]; acc_fma(acc, ((const uint4*)(G + (long)s0 * 128))[lane], dinv[s0]); }
        if (cd > CAP) {  // rare overflow
            int oc = *ovfcnt; oc = oc < OVF_MAX ? oc : OVF_MAX;
            for (int j = 0; j < oc; ++j)
                if (ovf[2 * j] == node) {
                    int s0 = ovf[2 * j + 1];
                    acc_fma(acc, ((const uint4*)(G + (long)s0 * 128))[lane], dinv[s0]);
                }
        }
        const int c0 = lane * 8;
        float o[8];
#pragma unroll
        for (int c = 0; c < 8; ++c) {
            float v = wself * acc[c] + b1s[c0 + c];
            o[c] = v > 0.f ? v : 0.f;
        }
        hv.x = pack2(o[0], o[1]); hv.y = pack2(o[2], o[3]);
        hv.z = pack2(o[4], o[5]); hv.w = pack2(o[6], o[7]);
    }
    ((uint4*)(Hs + grp * 136))[lane] = hv;   // zero rows for node>=N
    __syncthreads();

    // ---- phase 2: 16x64 GEMM, one 16-col tile per wave ----
    const int wv = tid >> 6, l64 = tid & 63;
    const int mm = l64 & 15, qd = l64 >> 4;
    s16x8 af[4];
#pragma unroll
    for (int kc = 0; kc < 4; ++kc)
        af[kc] = *(const s16x8*)&Hs[mm * 136 + kc * 32 + qd * 8];
    f32x4 acc = {0.f, 0.f, 0.f, 0.f};
#pragma unroll
    for (int kc = 0; kc < 4; ++kc) {
        s16x8 bf_ = *(const s16x8*)&Wt[(wv * 16 + mm) * 136 + kc * 32 + qd * 8];
        acc = __builtin_amdgcn_mfma_f32_16x16x32_bf16(af[kc], bf_, acc, 0, 0, 0);
    }
#pragma unroll
    for (int r = 0; r < 4; ++r) {
        int grow = blockIdx.x * 16 + qd * 4 + r;
        if (grow < N) G2[(long)grow * 64 + wv * 16 + mm] = __float2bfloat16(acc[r]);
    }
}

// Final gather: out[d,:64] = dinv[d]*(sum dinv[s]*g2[s,:]) + b2
__global__ __launch_bounds__(256) void k_gather2(const __hip_bfloat16* __restrict__ G2,
                                                 const int* __restrict__ cnt,
                                                 const int* __restrict__ slots,
                                                 const int* __restrict__ ovf,
                                                 const int* __restrict__ ovfcnt,
                                                 const float* __restrict__ dinv,
                                                 const void* __restrict__ b2,
                                                 void* __restrict__ outp,
                                                 const int* __restrict__ flags, int N) {
    const int tid = threadIdx.x;
    const int grp = tid >> 3, lane = tid & 7;
    const int node = blockIdx.x * 32 + grp;
    if (node >= N) return;
    const float wself = dinv[node];
    float acc[8] = {0, 0, 0, 0, 0, 0, 0, 0};
    acc_fma(acc, ((const uint4*)(G2 + (long)node * 64))[lane], wself);
    const int cd = cnt[node];
    const int m = cd < CAP ? cd : CAP;
    const int* sl = slots + (long)node * CAP;
    int i = 0;
    for (; i + 1 < m; i += 2) {
        int s0 = sl[i], s1 = sl[i + 1];
        float w0 = dinv[s0], w1 = dinv[s1];
        uint4 v0 = ((const uint4*)(G2 + (long)s0 * 64))[lane];
        uint4 v1 = ((const uint4*)(G2 + (long)s1 * 64))[lane];
        acc_fma(acc, v0, w0); acc_fma(acc, v1, w1);
    }
    if (i < m) { int s0 = sl[i]; acc_fma(acc, ((const uint4*)(G2 + (long)s0 * 64))[lane], dinv[s0]); }
    if (cd > CAP) {
        int oc = *ovfcnt; oc = oc < OVF_MAX ? oc : OVF_MAX;
        for (int j = 0; j < oc; ++j)
            if (ovf[2 * j] == node) {
                int s0 = ovf[2 * j + 1];
                acc_fma(acc, ((const uint4*)(G2 + (long)s0 * 64))[lane], dinv[s0]);
            }
    }
    const bool f32m = flags[0] != 0;
    const int c0 = lane * 8;
    float bv[8];
    if (f32m) {
        const float4* bp = (const float4*)((const float*)b2 + c0);
        float4 b0 = bp[0], b1v = bp[1];
        bv[0] = b0.x; bv[1] = b0.y; bv[2] = b0.z; bv[3] = b0.w;
        bv[4] = b1v.x; bv[5] = b1v.y; bv[6] = b1v.z; bv[7] = b1v.w;
    } else {
        uint4 b = *(const uint4*)((const __hip_bfloat16*)b2 + c0);
        bv[0] = lo2f(b.x); bv[1] = hi2f(b.x); bv[2] = lo2f(b.y); bv[3] = hi2f(b.y);
        bv[4] = lo2f(b.z); bv[5] = hi2f(b.z); bv[6] = lo2f(b.w); bv[7] = hi2f(b.w);
    }
    float o[8];
#pragma unroll
    for (int c = 0; c < 8; ++c) o[c] = wself * acc[c] + bv[c];
    if (!f32m) {
        uint4 pv = { pack2(o[0], o[1]), pack2(o[2], o[3]), pack2(o[4], o[5]), pack2(o[6], o[7]) };
        ((uint4*)outp)[(long)node * 8 + lane] = pv;
    } else {
        float4* op = (float4*)((float*)outp + (long)node * 64 + c0);
        op[0] = make_float4(o[0], o[1], o[2], o[3]);
        op[1] = make_float4(o[4], o[5], o[6], o[7]);
    }
}

extern "C" void kernel_launch(void* const* d_in, const int* in_sizes, int n_in,
                              void* d_out, int out_size, void* d_ws, size_t ws_size,
                              hipStream_t stream) {
    const void* x  = d_in[0];
    const int*  ei = (const int*)d_in[1];
    const void* W1 = d_in[2];
    const void* b1 = d_in[3];
    const void* W2 = d_in[4];
    const void* b2 = d_in[5];

    const int N = in_sizes[0] / FIN;   // 50000
    const int E = in_sizes[1] / 2;     // 800000

    // ws layout (bytes), ~28MB total:
    //   flags @0, cnt @4096 (4N), ovfcnt right after cnt, dinv @262144,
    //   ovf @524288 (1.5MB), slots @2097152 (9.6MB),
    //   g @11730944 (12.8MB), g2 @24530944 (6.4MB)
    char* ws = (char*)d_ws;
    int*   flags  = (int*)ws;
    int*   cnt    = (int*)(ws + 4096);
    int*   ovfcnt = (int*)(ws + 4096 + (size_t)N * 4);
    float* dinv   = (float*)(ws + 262144);
    int*   ovf    = (int*)(ws + 524288);
    int*   slots  = (int*)(ws + 2097152);
    __hip_bfloat16* g  = (__hip_bfloat16*)(ws + 11730944);
    __hip_bfloat16* g2 = (__hip_bfloat16*)(ws + 24530944);

    k_detect<<<1, 256, 0, stream>>>((const unsigned*)x, ei, E, flags);
    hipMemsetAsync(cnt, 0, (size_t)N * 4 + 4, stream);  // cnt + ovfcnt

    const int GB = (N + 63) / 64;
    k_fused1<<<GB, 256, 0, stream>>>(x, W1, ei, E, N, cnt, slots, ovf, ovfcnt, g, flags);
    k_dinv<<<(N + 255) / 256, 256, 0, stream>>>(cnt, dinv, N);
    k_gg<<<(N + 15) / 16, 256, 0, stream>>>(g, cnt, slots, ovf, ovfcnt, dinv, b1, W2, g2, flags, N);
    k_gather2<<<(N + 31) / 32, 256, 0, stream>>>(g2, cnt, slots, ovf, ovfcnt, dinv, b2, d_out, flags, N);
}

// Round 7
// 242.340 us; speedup vs baseline: 1.0480x; 1.0480x over previous
//
#include <hip/hip_runtime.h>
#include <hip/hip_bf16.h>

// GCN 2-layer encoder. R7: revert build+gemm1 fusion (barrier drain serialized
// it); separate k_build (write-drain bound, max TLP) + MFMA gemm1. Keep
// gather1+gemm2 fusion (k_gg). 4-deep ILP in gathers.
// out[d] = dinv[d] * sum_{s in N(d) U {d}} dinv[s]*h[s] + b,  h = in @ W
// dinv = rsqrt(1 + indeg).

constexpr int FIN = 128;
constexpr int HID = 128;
constexpr int FOUT = 64;
constexpr int CAP = 48;          // adjacency slots per node (Poisson(16) max ~36)
constexpr int OVF_MAX = 196608;  // overflow pairs capacity

typedef __attribute__((ext_vector_type(8))) short s16x8;
typedef __attribute__((ext_vector_type(4))) float f32x4;

static __device__ __forceinline__ float bf2f(__hip_bfloat16 v) { return __bfloat162float(v); }
static __device__ __forceinline__ float lo2f(unsigned u) { union { unsigned i; float f; } c; c.i = u << 16; return c.f; }
static __device__ __forceinline__ float hi2f(unsigned u) { union { unsigned i; float f; } c; c.i = u & 0xffff0000u; return c.f; }
static __device__ __forceinline__ unsigned short f2bfu(float f) {
    __hip_bfloat16 h = __float2bfloat16(f);
    union { __hip_bfloat16 h; unsigned short u; } c; c.h = h; return c.u;
}
static __device__ __forceinline__ unsigned pack2(float a, float b) {
    return (unsigned)f2bfu(a) | ((unsigned)f2bfu(b) << 16);
}
static __device__ __forceinline__ void acc_fma(float* acc, uint4 v, float w) {
    acc[0] += w * lo2f(v.x); acc[1] += w * hi2f(v.x);
    acc[2] += w * lo2f(v.y); acc[3] += w * hi2f(v.y);
    acc[4] += w * lo2f(v.z); acc[5] += w * hi2f(v.z);
    acc[6] += w * lo2f(v.w); acc[7] += w * hi2f(v.w);
}

// flags + zero cnt/ovfcnt. Block 0 detects dtypes; all blocks zero cnt.
__global__ __launch_bounds__(256) void k_detect(const unsigned* __restrict__ xw,
                                                const int* __restrict__ eiw,
                                                int E, int* __restrict__ flags,
                                                int* __restrict__ cnt, int N) {
    // zero cnt region (cnt[N] is ovfcnt)
    for (long i = (long)blockIdx.x * 256 + threadIdx.x; i <= N; i += (long)gridDim.x * 256)
        cnt[i] = 0;
    if (blockIdx.x != 0) return;
    __shared__ int s_bf16like, s_oddnz;
    if (threadIdx.x == 0) { s_bf16like = 0; s_oddnz = 0; }
    __syncthreads();
    int c = 0;
    for (int i = threadIdx.x; i < 4096; i += 256) {
        unsigned ex = ((xw[i] & 0xffffu) >> 7) & 0xffu;
        if (ex >= 117u && ex <= 130u) c++;
    }
    atomicAdd(&s_bf16like, c);
    int nz = 0;
    for (int i = threadIdx.x; i < 2048; i += 256)
        if (eiw[2 * i + 1] != 0) nz++;
    atomicAdd(&s_oddnz, nz);
    __syncthreads();
    if (threadIdx.x == 0) {
        flags[0] = (s_bf16like < 2048) ? 1 : 0;
        flags[1] = (s_oddnz == 0) ? 1 : 0;
    }
}

// single pass adjacency build: cnt[d]++, slot write (or overflow spill)
__global__ __launch_bounds__(256) void k_build(const int* __restrict__ ei, int E, int N,
                                               int* __restrict__ cnt,
                                               int* __restrict__ slots,
                                               int* __restrict__ ovf,
                                               int* __restrict__ ovfcnt,
                                               const int* __restrict__ flags) {
    long i = (long)blockIdx.x * 256 + threadIdx.x;
    if (i >= E) return;
    int s, d;
    if (flags[1]) {
        s = ((const int2*)ei)[i].x;
        d = ((const int2*)(ei + 2 * (long)E))[i].x;
    } else {
        s = ei[i];
        d = ei[(long)E + i];
    }
    if ((unsigned)s >= (unsigned)N || (unsigned)d >= (unsigned)N) return;
    int pos = atomicAdd(&cnt[d], 1);
    if (pos < CAP) {
        slots[(long)d * CAP + pos] = s;
    } else {
        int op = atomicAdd(ovfcnt, 1);
        if (op < OVF_MAX) { ovf[2 * op] = d; ovf[2 * op + 1] = s; }
    }
}

__global__ __launch_bounds__(256) void k_dinv(const int* __restrict__ cnt,
                                              float* __restrict__ dinv, int N) {
    int i = blockIdx.x * blockDim.x + threadIdx.x;
    if (i < N) dinv[i] = rsqrtf((float)(cnt[i] + 1));  // +1 self loop
}

// MFMA GEMM1: g[row,:128] = bf16( X[row,:128] @ W1[:128,:128] )  (UNscaled)
__global__ __launch_bounds__(256) void k_gemm1(const void* __restrict__ Xp,
                                               const void* __restrict__ Wp,
                                               __hip_bfloat16* __restrict__ G,
                                               const int* __restrict__ flags, int N) {
    __shared__ __align__(16) short Wt[128 * 136];   // W1^T bf16, pad 128->136
    const bool f32m = flags[0] != 0;
    const int tid = threadIdx.x;
    for (int i = tid; i < 128 * 128; i += 256) {
        int k = i >> 7, n = i & 127;
        float wv = f32m ? ((const float*)Wp)[(long)k * 128 + n]
                        : bf2f(((const __hip_bfloat16*)Wp)[(long)k * 128 + n]);
        Wt[n * 136 + k] = (short)f2bfu(wv);
    }
    __syncthreads();
    const int w = tid >> 6, lane = tid & 63;
    const int m = lane & 15, quad = lane >> 4;
    const int rowA = blockIdx.x * 64 + w * 16 + m;
    const int rowc = rowA < N ? rowA : N - 1;
    s16x8 afr[4];
#pragma unroll
    for (int kc = 0; kc < 4; ++kc) {
        const int k0 = kc * 32 + quad * 8;
        if (!f32m) {
            afr[kc] = *(const s16x8*)((const __hip_bfloat16*)Xp + (long)rowc * 128 + k0);
        } else {
            const float* p = (const float*)Xp + (long)rowc * 128 + k0;
            s16x8 t;
#pragma unroll
            for (int j = 0; j < 8; ++j) t[j] = (short)f2bfu(p[j]);
            afr[kc] = t;
        }
    }
    const int rbase = blockIdx.x * 64 + w * 16 + quad * 4;
#pragma unroll
    for (int ct = 0; ct < 8; ++ct) {
        f32x4 acc = {0.f, 0.f, 0.f, 0.f};
#pragma unroll
        for (int kc = 0; kc < 4; ++kc) {
            s16x8 bfr = *(const s16x8*)&Wt[(ct * 16 + m) * 136 + kc * 32 + quad * 8];
            acc = __builtin_amdgcn_mfma_f32_16x16x32_bf16(afr[kc], bfr, acc, 0, 0, 0);
        }
#pragma unroll
        for (int r = 0; r < 4; ++r) {
            int rr = rbase + r;
            if (rr < N) G[(long)rr * 128 + ct * 16 + m] = __float2bfloat16(acc[r]);
        }
    }
}

// Fused gather1 + GEMM2: per block, 16 nodes.
// h1[n,:] = relu( dinv[n]*(sum_s dinv[s]*g[s,:]) + b1 )   (LDS bf16 tile)
// g2[n,:64] = bf16( h1[n,:] @ W2[:128,:64] )              (UNscaled)
__global__ __launch_bounds__(256) void k_gg(const __hip_bfloat16* __restrict__ G,
                                            const int* __restrict__ cnt,
                                            const int* __restrict__ slots,
                                            const int* __restrict__ ovf,
                                            const int* __restrict__ ovfcnt,
                                            const float* __restrict__ dinv,
                                            const void* __restrict__ b1,
                                            const void* __restrict__ W2,
                                            __hip_bfloat16* __restrict__ G2,
                                            const int* __restrict__ flags, int N) {
    __shared__ __align__(16) short Wt[64 * 136];    // W2^T bf16 (17.4 KB)
    __shared__ __align__(16) short Hs[16 * 136];    // h1 tile bf16 (4.4 KB)
    __shared__ float b1s[128];
    const bool f32m = flags[0] != 0;
    const int tid = threadIdx.x;
    for (int i = tid; i < 128 * 64; i += 256) {
        int k = i >> 6, n = i & 63;
        float wv = f32m ? ((const float*)W2)[(long)k * 64 + n]
                        : bf2f(((const __hip_bfloat16*)W2)[(long)k * 64 + n]);
        Wt[n * 136 + k] = (short)f2bfu(wv);
    }
    if (tid < 128)
        b1s[tid] = f32m ? ((const float*)b1)[tid] : bf2f(((const __hip_bfloat16*)b1)[tid]);

    // ---- phase 1: gather (16 lanes per node, 8 cols each), 4-deep ILP ----
    const int grp = tid >> 4, lane = tid & 15;
    const int node = blockIdx.x * 16 + grp;
    uint4 hv = {0, 0, 0, 0};
    if (node < N) {
        const float wself = dinv[node];
        float acc[8] = {0, 0, 0, 0, 0, 0, 0, 0};
        acc_fma(acc, ((const uint4*)(G + (long)node * 128))[lane], wself);  // self loop
        const int cd = cnt[node];
        const int m = cd < CAP ? cd : CAP;
        const int* sl = slots + (long)node * CAP;
        int i = 0;
        for (; i + 3 < m; i += 4) {
            int s0 = sl[i], s1 = sl[i + 1], s2 = sl[i + 2], s3 = sl[i + 3];
            float w0 = dinv[s0], w1 = dinv[s1], w2 = dinv[s2], w3 = dinv[s3];
            uint4 v0 = ((const uint4*)(G + (long)s0 * 128))[lane];
            uint4 v1 = ((const uint4*)(G + (long)s1 * 128))[lane];
            uint4 v2 = ((const uint4*)(G + (long)s2 * 128))[lane];
            uint4 v3 = ((const uint4*)(G + (long)s3 * 128))[lane];
            acc_fma(acc, v0, w0); acc_fma(acc, v1, w1);
            acc_fma(acc, v2, w2); acc_fma(acc, v3, w3);
        }
        for (; i < m; ++i) {
            int s0 = sl[i];
            acc_fma(acc, ((const uint4*)(G + (long)s0 * 128))[lane], dinv[s0]);
        }
        if (cd > CAP) {  // rare overflow
            int oc = *ovfcnt; oc = oc < OVF_MAX ? oc : OVF_MAX;
            for (int j = 0; j < oc; ++j)
                if (ovf[2 * j] == node) {
                    int s0 = ovf[2 * j + 1];
                    acc_fma(acc, ((const uint4*)(G + (long)s0 * 128))[lane], dinv[s0]);
                }
        }
        const int c0 = lane * 8;
        float o[8];
#pragma unroll
        for (int c = 0; c < 8; ++c) {
            float v = wself * acc[c] + b1s[c0 + c];
            o[c] = v > 0.f ? v : 0.f;
        }
        hv.x = pack2(o[0], o[1]); hv.y = pack2(o[2], o[3]);
        hv.z = pack2(o[4], o[5]); hv.w = pack2(o[6], o[7]);
    }
    ((uint4*)(Hs + grp * 136))[lane] = hv;   // zero rows for node>=N
    __syncthreads();

    // ---- phase 2: 16x64 GEMM, one 16-col tile per wave ----
    const int wv = tid >> 6, l64 = tid & 63;
    const int mm = l64 & 15, qd = l64 >> 4;
    s16x8 af[4];
#pragma unroll
    for (int kc = 0; kc < 4; ++kc)
        af[kc] = *(const s16x8*)&Hs[mm * 136 + kc * 32 + qd * 8];
    f32x4 acc = {0.f, 0.f, 0.f, 0.f};
#pragma unroll
    for (int kc = 0; kc < 4; ++kc) {
        s16x8 bf_ = *(const s16x8*)&Wt[(wv * 16 + mm) * 136 + kc * 32 + qd * 8];
        acc = __builtin_amdgcn_mfma_f32_16x16x32_bf16(af[kc], bf_, acc, 0, 0, 0);
    }
#pragma unroll
    for (int r = 0; r < 4; ++r) {
        int grow = blockIdx.x * 16 + qd * 4 + r;
        if (grow < N) G2[(long)grow * 64 + wv * 16 + mm] = __float2bfloat16(acc[r]);
    }
}

// Final gather: out[d,:64] = dinv[d]*(sum dinv[s]*g2[s,:]) + b2
__global__ __launch_bounds__(256) void k_gather2(const __hip_bfloat16* __restrict__ G2,
                                                 const int* __restrict__ cnt,
                                                 const int* __restrict__ slots,
                                                 const int* __restrict__ ovf,
                                                 const int* __restrict__ ovfcnt,
                                                 const float* __restrict__ dinv,
                                                 const void* __restrict__ b2,
                                                 void* __restrict__ outp,
                                                 const int* __restrict__ flags, int N) {
    const int tid = threadIdx.x;
    const int grp = tid >> 3, lane = tid & 7;
    const int node = blockIdx.x * 32 + grp;
    if (node >= N) return;
    const float wself = dinv[node];
    float acc[8] = {0, 0, 0, 0, 0, 0, 0, 0};
    acc_fma(acc, ((const uint4*)(G2 + (long)node * 64))[lane], wself);
    const int cd = cnt[node];
    const int m = cd < CAP ? cd : CAP;
    const int* sl = slots + (long)node * CAP;
    int i = 0;
    for (; i + 3 < m; i += 4) {
        int s0 = sl[i], s1 = sl[i + 1], s2 = sl[i + 2], s3 = sl[i + 3];
        float w0 = dinv[s0], w1 = dinv[s1], w2 = dinv[s2], w3 = dinv[s3];
        uint4 v0 = ((const uint4*)(G2 + (long)s0 * 64))[lane];
        uint4 v1 = ((const uint4*)(G2 + (long)s1 * 64))[lane];
        uint4 v2 = ((const uint4*)(G2 + (long)s2 * 64))[lane];
        uint4 v3 = ((const uint4*)(G2 + (long)s3 * 64))[lane];
        acc_fma(acc, v0, w0); acc_fma(acc, v1, w1);
        acc_fma(acc, v2, w2); acc_fma(acc, v3, w3);
    }
    for (; i < m; ++i) {
        int s0 = sl[i];
        acc_fma(acc, ((const uint4*)(G2 + (long)s0 * 64))[lane], dinv[s0]);
    }
    if (cd > CAP) {
        int oc = *ovfcnt; oc = oc < OVF_MAX ? oc : OVF_MAX;
        for (int j = 0; j < oc; ++j)
            if (ovf[2 * j] == node) {
                int s0 = ovf[2 * j + 1];
                acc_fma(acc, ((const uint4*)(G2 + (long)s0 * 64))[lane], dinv[s0]);
            }
    }
    const bool f32m = flags[0] != 0;
    const int c0 = lane * 8;
    float bv[8];
    if (f32m) {
        const float4* bp = (const float4*)((const float*)b2 + c0);
        float4 b0 = bp[0], b1v = bp[1];
        bv[0] = b0.x; bv[1] = b0.y; bv[2] = b0.z; bv[3] = b0.w;
        bv[4] = b1v.x; bv[5] = b1v.y; bv[6] = b1v.z; bv[7] = b1v.w;
    } else {
        uint4 b = *(const uint4*)((const __hip_bfloat16*)b2 + c0);
        bv[0] = lo2f(b.x); bv[1] = hi2f(b.x); bv[2] = lo2f(b.y); bv[3] = hi2f(b.y);
        bv[4] = lo2f(b.z); bv[5] = hi2f(b.z); bv[6] = lo2f(b.w); bv[7] = hi2f(b.w);
    }
    float o[8];
#pragma unroll
    for (int c = 0; c < 8; ++c) o[c] = wself * acc[c] + bv[c];
    if (!f32m) {
        uint4 pv = { pack2(o[0], o[1]), pack2(o[2], o[3]), pack2(o[4], o[5]), pack2(o[6], o[7]) };
        ((uint4*)outp)[(long)node * 8 + lane] = pv;
    } else {
        float4* op = (float4*)((float*)outp + (long)node * 64 + c0);
        op[0] = make_float4(o[0], o[1], o[2], o[3]);
        op[1] = make_float4(o[4], o[5], o[6], o[7]);
    }
}

extern "C" void kernel_launch(void* const* d_in, const int* in_sizes, int n_in,
                              void* d_out, int out_size, void* d_ws, size_t ws_size,
                              hipStream_t stream) {
    const void* x  = d_in[0];
    const int*  ei = (const int*)d_in[1];
    const void* W1 = d_in[2];
    const void* b1 = d_in[3];
    const void* W2 = d_in[4];
    const void* b2 = d_in[5];

    const int N = in_sizes[0] / FIN;   // 50000
    const int E = in_sizes[1] / 2;     // 800000

    // ws layout (bytes), ~28MB total:
    //   flags @0, cnt @4096 (4N+4, last is ovfcnt), dinv @262144,
    //   ovf @524288 (1.5MB), slots @2097152 (9.6MB),
    //   g @11730944 (12.8MB), g2 @24530944 (6.4MB)
    char* ws = (char*)d_ws;
    int*   flags  = (int*)ws;
    int*   cnt    = (int*)(ws + 4096);
    int*   ovfcnt = cnt + N;
    float* dinv   = (float*)(ws + 262144);
    int*   ovf    = (int*)(ws + 524288);
    int*   slots  = (int*)(ws + 2097152);
    __hip_bfloat16* g  = (__hip_bfloat16*)(ws + 11730944);
    __hip_bfloat16* g2 = (__hip_bfloat16*)(ws + 24530944);

    const int EB = (E + 255) / 256;

    k_detect<<<64, 256, 0, stream>>>((const unsigned*)x, ei, E, flags, cnt, N);
    k_build<<<EB, 256, 0, stream>>>(ei, E, N, cnt, slots, ovf, ovfcnt, flags);
    k_dinv<<<(N + 255) / 256, 256, 0, stream>>>(cnt, dinv, N);
    k_gemm1<<<(N + 63) / 64, 256, 0, stream>>>(x, W1, g, flags, N);
    k_gg<<<(N + 15) / 16, 256, 0, stream>>>(g, cnt, slots, ovf, ovfcnt, dinv, b1, W2, g2, flags, N);
    k_gather2<<<(N + 31) / 32, 256, 0, stream>>>(g2, cnt, slots, ovf, ovfcnt, dinv, b2, d_out, flags, N);
}

// Round 8
// 230.502 us; speedup vs baseline: 1.1018x; 1.0514x over previous
//
#include <hip/hip_runtime.h>
#include <hip/hip_bf16.h>

// GCN 2-layer encoder. R8: LDS-free latency-optimized gathers (max occupancy),
// dinv pre-scaled into GEMM outputs (no per-edge dinv loads), inline rsqrt
// from cnt (no dinv array/kernel), standalone MFMA GEMMs.
// out[d] = dinv[d] * sum_{s in N(d) U {d}} g[s] + b,  g[s] = dinv[s]*(in@W)[s]
// dinv = rsqrt(1 + indeg).

constexpr int FIN = 128;
constexpr int HID = 128;
constexpr int FOUT = 64;
constexpr int CAP = 48;          // adjacency slots per node (Poisson(16) max ~36)
constexpr int OVF_MAX = 196608;  // overflow pairs capacity

typedef __attribute__((ext_vector_type(8))) short s16x8;
typedef __attribute__((ext_vector_type(4))) float f32x4;

static __device__ __forceinline__ float bf2f(__hip_bfloat16 v) { return __bfloat162float(v); }
static __device__ __forceinline__ float lo2f(unsigned u) { union { unsigned i; float f; } c; c.i = u << 16; return c.f; }
static __device__ __forceinline__ float hi2f(unsigned u) { union { unsigned i; float f; } c; c.i = u & 0xffff0000u; return c.f; }
static __device__ __forceinline__ unsigned short f2bfu(float f) {
    __hip_bfloat16 h = __float2bfloat16(f);
    union { __hip_bfloat16 h; unsigned short u; } c; c.h = h; return c.u;
}
static __device__ __forceinline__ unsigned pack2(float a, float b) {
    return (unsigned)f2bfu(a) | ((unsigned)f2bfu(b) << 16);
}
static __device__ __forceinline__ void acc_add(float* acc, uint4 v) {
    acc[0] += lo2f(v.x); acc[1] += hi2f(v.x);
    acc[2] += lo2f(v.y); acc[3] += hi2f(v.y);
    acc[4] += lo2f(v.z); acc[5] += hi2f(v.z);
    acc[6] += lo2f(v.w); acc[7] += hi2f(v.w);
}

// flags + zero cnt/ovfcnt. Block 0 detects dtypes; all blocks zero cnt.
__global__ __launch_bounds__(256) void k_detect(const unsigned* __restrict__ xw,
                                                const int* __restrict__ eiw,
                                                int E, int* __restrict__ flags,
                                                int* __restrict__ cnt, int N) {
    for (long i = (long)blockIdx.x * 256 + threadIdx.x; i <= N; i += (long)gridDim.x * 256)
        cnt[i] = 0;
    if (blockIdx.x != 0) return;
    __shared__ int s_bf16like, s_oddnz;
    if (threadIdx.x == 0) { s_bf16like = 0; s_oddnz = 0; }
    __syncthreads();
    int c = 0;
    for (int i = threadIdx.x; i < 4096; i += 256) {
        unsigned ex = ((xw[i] & 0xffffu) >> 7) & 0xffu;
        if (ex >= 117u && ex <= 130u) c++;
    }
    atomicAdd(&s_bf16like, c);
    int nz = 0;
    for (int i = threadIdx.x; i < 2048; i += 256)
        if (eiw[2 * i + 1] != 0) nz++;
    atomicAdd(&s_oddnz, nz);
    __syncthreads();
    if (threadIdx.x == 0) {
        flags[0] = (s_bf16like < 2048) ? 1 : 0;
        flags[1] = (s_oddnz == 0) ? 1 : 0;
    }
}

// single pass adjacency build: cnt[d]++, slot write (or overflow spill)
__global__ __launch_bounds__(256) void k_build(const int* __restrict__ ei, int E, int N,
                                               int* __restrict__ cnt,
                                               int* __restrict__ slots,
                                               int* __restrict__ ovf,
                                               int* __restrict__ ovfcnt,
                                               const int* __restrict__ flags) {
    long i = (long)blockIdx.x * 256 + threadIdx.x;
    if (i >= E) return;
    int s, d;
    if (flags[1]) {
        s = ((const int2*)ei)[i].x;
        d = ((const int2*)(ei + 2 * (long)E))[i].x;
    } else {
        s = ei[i];
        d = ei[(long)E + i];
    }
    if ((unsigned)s >= (unsigned)N || (unsigned)d >= (unsigned)N) return;
    int pos = atomicAdd(&cnt[d], 1);
    if (pos < CAP) {
        slots[(long)d * CAP + pos] = s;
    } else {
        int op = atomicAdd(ovfcnt, 1);
        if (op < OVF_MAX) { ovf[2 * op] = d; ovf[2 * op + 1] = s; }
    }
}

// MFMA GEMM: G[row,:C] = bf16( rsqrt(cnt[row]+1) * (X[row,:128] @ W[:128,:C]) )
// CT = C/16 col tiles. 64 rows/block, 4 waves. X bf16 unless (xf32flag && f32 mode).
template<int CT>
__global__ __launch_bounds__(256) void k_gemm(const void* __restrict__ Xp, int x_follows_flag,
                                              const void* __restrict__ Wp,
                                              const int* __restrict__ cnt,
                                              __hip_bfloat16* __restrict__ G,
                                              const int* __restrict__ flags, int N) {
    constexpr int C = CT * 16;
    __shared__ __align__(16) short Wt[C * 136];   // W^T bf16, pad 128->136
    const bool f32m = flags[0] != 0;
    const bool xf32 = (x_follows_flag != 0) && f32m;
    const int tid = threadIdx.x;
    for (int i = tid; i < 128 * C; i += 256) {
        int k = i / C, n = i % C;
        float wv = f32m ? ((const float*)Wp)[(long)k * C + n]
                        : bf2f(((const __hip_bfloat16*)Wp)[(long)k * C + n]);
        Wt[n * 136 + k] = (short)f2bfu(wv);
    }
    __syncthreads();
    const int w = tid >> 6, lane = tid & 63;
    const int m = lane & 15, quad = lane >> 4;
    const int rowA = blockIdx.x * 64 + w * 16 + m;
    const int rowc = rowA < N ? rowA : N - 1;
    s16x8 afr[4];
#pragma unroll
    for (int kc = 0; kc < 4; ++kc) {
        const int k0 = kc * 32 + quad * 8;
        if (!xf32) {
            afr[kc] = *(const s16x8*)((const __hip_bfloat16*)Xp + (long)rowc * 128 + k0);
        } else {
            const float* p = (const float*)Xp + (long)rowc * 128 + k0;
            s16x8 t;
#pragma unroll
            for (int j = 0; j < 8; ++j) t[j] = (short)f2bfu(p[j]);
            afr[kc] = t;
        }
    }
    const int rbase = blockIdx.x * 64 + w * 16 + quad * 4;
    float dv[4];
#pragma unroll
    for (int r = 0; r < 4; ++r) {
        int rr = min(rbase + r, N - 1);
        dv[r] = rsqrtf((float)(cnt[rr] + 1));
    }
#pragma unroll
    for (int ct = 0; ct < CT; ++ct) {
        f32x4 acc = {0.f, 0.f, 0.f, 0.f};
#pragma unroll
        for (int kc = 0; kc < 4; ++kc) {
            s16x8 bfr = *(const s16x8*)&Wt[(ct * 16 + m) * 136 + kc * 32 + quad * 8];
            acc = __builtin_amdgcn_mfma_f32_16x16x32_bf16(afr[kc], bfr, acc, 0, 0, 0);
        }
#pragma unroll
        for (int r = 0; r < 4; ++r) {
            int rr = rbase + r;
            if (rr < N) G[(long)rr * C + ct * 16 + m] = __float2bfloat16(dv[r] * acc[r]);
        }
    }
}

// LDS-free gather. OUT[d,:F] = act( rsqrt(cnt[d]+1) * (G[d,:] + sum_s G[s,:]) + bias )
// F=128: 16 lanes/node, 16 nodes/block. F=64: 8 lanes/node, 32 nodes/block.
// layer1: relu + bf16 out. layer2: linear + (f32|bf16 per flags) out.
template<int F, int LAYER1>
__global__ __launch_bounds__(256) void k_gather(const __hip_bfloat16* __restrict__ G,
                                                const int* __restrict__ cnt,
                                                const int* __restrict__ slots,
                                                const int* __restrict__ ovf,
                                                const int* __restrict__ ovfcnt,
                                                const void* __restrict__ bias,
                                                void* __restrict__ outp,
                                                const int* __restrict__ flags, int N) {
    constexpr int L = F / 8;
    constexpr int NODES = 256 / L;
    const int tid = threadIdx.x;
    const int grp = tid / L, lane = tid % L;
    const int node = blockIdx.x * NODES + grp;
    if (node >= N) return;
    const int cd = cnt[node];
    const float wself = rsqrtf((float)(cd + 1));
    const int m = cd < CAP ? cd : CAP;
    const int* sl = slots + (long)node * CAP;
    float acc[8] = {0, 0, 0, 0, 0, 0, 0, 0};
    acc_add(acc, ((const uint4*)(G + (long)node * F))[lane]);   // self loop
    int i = 0;
    for (; i + 3 < m; i += 4) {
        int s0 = sl[i], s1 = sl[i + 1], s2 = sl[i + 2], s3 = sl[i + 3];
        uint4 v0 = ((const uint4*)(G + (long)s0 * F))[lane];
        uint4 v1 = ((const uint4*)(G + (long)s1 * F))[lane];
        uint4 v2 = ((const uint4*)(G + (long)s2 * F))[lane];
        uint4 v3 = ((const uint4*)(G + (long)s3 * F))[lane];
        acc_add(acc, v0); acc_add(acc, v1); acc_add(acc, v2); acc_add(acc, v3);
    }
    for (; i < m; ++i)
        acc_add(acc, ((const uint4*)(G + (long)sl[i] * F))[lane]);
    if (cd > CAP) {  // rare overflow
        int oc = *ovfcnt; oc = oc < OVF_MAX ? oc : OVF_MAX;
        for (int j = 0; j < oc; ++j)
            if (ovf[2 * j] == node)
                acc_add(acc, ((const uint4*)(G + (long)ovf[2 * j + 1] * F))[lane]);
    }
    const bool f32m = flags[0] != 0;
    const int c0 = lane * 8;
    float bv[8];
    if (f32m) {
        const float4* bp = (const float4*)((const float*)bias + c0);
        float4 b0 = bp[0], b1 = bp[1];
        bv[0] = b0.x; bv[1] = b0.y; bv[2] = b0.z; bv[3] = b0.w;
        bv[4] = b1.x; bv[5] = b1.y; bv[6] = b1.z; bv[7] = b1.w;
    } else {
        uint4 b = *(const uint4*)((const __hip_bfloat16*)bias + c0);
        bv[0] = lo2f(b.x); bv[1] = hi2f(b.x); bv[2] = lo2f(b.y); bv[3] = hi2f(b.y);
        bv[4] = lo2f(b.z); bv[5] = hi2f(b.z); bv[6] = lo2f(b.w); bv[7] = hi2f(b.w);
    }
    float o[8];
#pragma unroll
    for (int c = 0; c < 8; ++c) {
        float v = wself * acc[c] + bv[c];
        o[c] = (LAYER1 && v < 0.f) ? 0.f : v;
    }
    if (LAYER1 || !f32m) {
        uint4 pv = { pack2(o[0], o[1]), pack2(o[2], o[3]), pack2(o[4], o[5]), pack2(o[6], o[7]) };
        ((uint4*)outp)[(long)node * L + lane] = pv;
    } else {
        float4* op = (float4*)((float*)outp + (long)node * F + c0);
        op[0] = make_float4(o[0], o[1], o[2], o[3]);
        op[1] = make_float4(o[4], o[5], o[6], o[7]);
    }
}

extern "C" void kernel_launch(void* const* d_in, const int* in_sizes, int n_in,
                              void* d_out, int out_size, void* d_ws, size_t ws_size,
                              hipStream_t stream) {
    const void* x  = d_in[0];
    const int*  ei = (const int*)d_in[1];
    const void* W1 = d_in[2];
    const void* b1 = d_in[3];
    const void* W2 = d_in[4];
    const void* b2 = d_in[5];

    const int N = in_sizes[0] / FIN;   // 50000
    const int E = in_sizes[1] / 2;     // 800000

    // ws layout (bytes), ~34MB:
    //   flags @0, cnt @4096 (4N+4, last is ovfcnt),
    //   ovf @524288 (1.5MB), slots @2097152 (9.6MB),
    //   g @11730944 (12.8MB), h1 @24530944 (12.8MB), g2 @37330944 (6.4MB)
    char* ws = (char*)d_ws;
    int*   flags  = (int*)ws;
    int*   cnt    = (int*)(ws + 4096);
    int*   ovfcnt = cnt + N;
    int*   ovf    = (int*)(ws + 524288);
    int*   slots  = (int*)(ws + 2097152);
    __hip_bfloat16* g  = (__hip_bfloat16*)(ws + 11730944);
    __hip_bfloat16* h1 = (__hip_bfloat16*)(ws + 24530944);
    __hip_bfloat16* g2 = (__hip_bfloat16*)(ws + 37330944);

    const int EB = (E + 255) / 256;
    const int GB = (N + 63) / 64;

    k_detect<<<64, 256, 0, stream>>>((const unsigned*)x, ei, E, flags, cnt, N);
    k_build<<<EB, 256, 0, stream>>>(ei, E, N, cnt, slots, ovf, ovfcnt, flags);
    // layer 1
    k_gemm<8><<<GB, 256, 0, stream>>>(x, 1, W1, cnt, g, flags, N);
    k_gather<128, 1><<<(N + 15) / 16, 256, 0, stream>>>(g, cnt, slots, ovf, ovfcnt, b1, h1, flags, N);
    // layer 2
    k_gemm<4><<<GB, 256, 0, stream>>>(h1, 0, W2, cnt, g2, flags, N);
    k_gather<64, 0><<<(N + 31) / 32, 256, 0, stream>>>(g2, cnt, slots, ovf, ovfcnt, b2, d_out, flags, N);
}

// Round 9
// 204.727 us; speedup vs baseline: 1.2406x; 1.1259x over previous
//
#include <hip/hip_runtime.h>
#include <hip/hip_bf16.h>

// GCN 2-layer encoder. R9: two-phase bucketed adjacency build — phase A
// radix-partitions edges into 98-node destination buckets with block-level
// contiguous reservations (dense line writes); phase B builds cnt/slots per
// bucket in LDS and writes out densely. Replaces the 47.6MB-random-write
// k_build (56us). Gathers/GEMMs unchanged from R8.
// out[d] = dinv[d] * sum_{s in N(d) U {d}} g[s] + b,  g[s] = dinv[s]*(in@W)[s]

constexpr int FIN = 128;
constexpr int HID = 128;
constexpr int FOUT = 64;
constexpr int CAP = 48;     // adjacency slots per node
constexpr int NPB = 98;     // nodes per bucket
constexpr int BCAP = 3072;  // pairs per bucket region (mean ~1570 at E=800k)
constexpr int OVF_MAX = 65536;

typedef __attribute__((ext_vector_type(8))) short s16x8;
typedef __attribute__((ext_vector_type(4))) float f32x4;

static __device__ __forceinline__ float bf2f(__hip_bfloat16 v) { return __bfloat162float(v); }
static __device__ __forceinline__ float lo2f(unsigned u) { union { unsigned i; float f; } c; c.i = u << 16; return c.f; }
static __device__ __forceinline__ float hi2f(unsigned u) { union { unsigned i; float f; } c; c.i = u & 0xffff0000u; return c.f; }
static __device__ __forceinline__ unsigned short f2bfu(float f) {
    __hip_bfloat16 h = __float2bfloat16(f);
    union { __hip_bfloat16 h; unsigned short u; } c; c.h = h; return c.u;
}
static __device__ __forceinline__ unsigned pack2(float a, float b) {
    return (unsigned)f2bfu(a) | ((unsigned)f2bfu(b) << 16);
}
static __device__ __forceinline__ void acc_add(float* acc, uint4 v) {
    acc[0] += lo2f(v.x); acc[1] += hi2f(v.x);
    acc[2] += lo2f(v.y); acc[3] += hi2f(v.y);
    acc[4] += lo2f(v.z); acc[5] += hi2f(v.z);
    acc[6] += lo2f(v.w); acc[7] += hi2f(v.w);
}

// flags detect + zero bucket cursors / overflow counters (1 block).
__global__ __launch_bounds__(256) void k_detect(const unsigned* __restrict__ xw,
                                                const int* __restrict__ eiw,
                                                int E, int* __restrict__ flags,
                                                int* __restrict__ gcur) {
    for (int i = threadIdx.x; i < 1026; i += 256) gcur[i] = 0;  // gcur[1024]+ovfAcnt+ovf2cnt
    __shared__ int s_bf16like, s_oddnz;
    if (threadIdx.x == 0) { s_bf16like = 0; s_oddnz = 0; }
    __syncthreads();
    int c = 0;
    for (int i = threadIdx.x; i < 4096; i += 256) {
        unsigned ex = ((xw[i] & 0xffffu) >> 7) & 0xffu;
        if (ex >= 117u && ex <= 130u) c++;
    }
    atomicAdd(&s_bf16like, c);
    int nz = 0;
    for (int i = threadIdx.x; i < 2048; i += 256)
        if (eiw[2 * i + 1] != 0) nz++;
    atomicAdd(&s_oddnz, nz);
    __syncthreads();
    if (threadIdx.x == 0) {
        flags[0] = (s_bf16like < 2048) ? 1 : 0;
        flags[1] = (s_oddnz == 0) ? 1 : 0;
    }
}

// Phase A: partition edges into destination buckets with per-block contiguous
// reservations. 4096 edges/block.
__global__ __launch_bounds__(256) void k_binA(const int* __restrict__ ei, int E, int N,
                                              int nbuk,
                                              int* __restrict__ gcur,
                                              int2* __restrict__ pairs,
                                              int2* __restrict__ ovfA,
                                              int* __restrict__ ovfAcnt,
                                              const int* __restrict__ flags) {
    __shared__ int hist[1024];
    __shared__ int gbase[1024];
    const int tid = threadIdx.x;
    const long base = (long)blockIdx.x * 4096;
    const bool i64 = flags[1] != 0;
    for (int b = tid; b < nbuk; b += 256) hist[b] = 0;
    __syncthreads();
    // pass 1: histogram
    for (int j = 0; j < 16; ++j) {
        long i = base + j * 256 + tid;
        if (i >= E) break;
        int s, d;
        if (i64) { s = ((const int2*)ei)[i].x; d = ((const int2*)(ei + 2 * (long)E))[i].x; }
        else     { s = ei[i]; d = ei[(long)E + i]; }
        if ((unsigned)s >= (unsigned)N || (unsigned)d >= (unsigned)N) continue;
        atomicAdd(&hist[d / NPB], 1);
    }
    __syncthreads();
    // reserve contiguous slices; reuse hist as relative cursor
    for (int b = tid; b < nbuk; b += 256) {
        int h = hist[b];
        gbase[b] = h > 0 ? atomicAdd(&gcur[b], h) : 0;
        hist[b] = 0;
    }
    __syncthreads();
    // pass 2: scatter pairs into reserved slices
    for (int j = 0; j < 16; ++j) {
        long i = base + j * 256 + tid;
        if (i >= E) break;
        int s, d;
        if (i64) { s = ((const int2*)ei)[i].x; d = ((const int2*)(ei + 2 * (long)E))[i].x; }
        else     { s = ei[i]; d = ei[(long)E + i]; }
        if ((unsigned)s >= (unsigned)N || (unsigned)d >= (unsigned)N) continue;
        int b = d / NPB;
        int p = gbase[b] + atomicAdd(&hist[b], 1);
        if (p < BCAP) {
            pairs[(long)b * BCAP + p] = make_int2(d, s);
        } else {
            int op = atomicAdd(ovfAcnt, 1);
            if (op < OVF_MAX) ovfA[op] = make_int2(d, s);
        }
    }
}

// Phase B: per bucket, build cnt+slots in LDS, dense writeout.
__global__ __launch_bounds__(256) void k_binB(const int* __restrict__ gcur,
                                              const int2* __restrict__ pairs,
                                              int* __restrict__ cnt,
                                              int* __restrict__ slots,
                                              int2* __restrict__ ovf2,
                                              int* __restrict__ ovf2cnt, int N) {
    __shared__ int cntL[NPB];
    __shared__ __align__(16) int slotsL[NPB * CAP];
    const int b = blockIdx.x;
    const int tid = threadIdx.x;
    const int d0 = b * NPB;
    const int nd = min(NPB, N - d0);
    if (nd <= 0) return;
    for (int i = tid; i < NPB; i += 256) cntL[i] = 0;
    __syncthreads();
    const int c = min(gcur[b], BCAP);
    const int2* pb = pairs + (long)b * BCAP;
    for (int i = tid; i < c; i += 256) {
        int2 p = pb[i];
        int ld = p.x - d0;
        int pos = atomicAdd(&cntL[ld], 1);
        if (pos < CAP) {
            slotsL[ld * CAP + pos] = p.y;
        } else {
            int op = atomicAdd(ovf2cnt, 1);
            if (op < OVF_MAX) ovf2[op] = p;
        }
    }
    __syncthreads();
    for (int i = tid; i < nd; i += 256) cnt[d0 + i] = cntL[i];
    const uint4* sv = (const uint4*)slotsL;
    uint4* gv = (uint4*)(slots + (long)d0 * CAP);   // d0*CAP*4 = b*18816, 16B aligned
    const int total4 = (nd * CAP) >> 2;             // CAP divisible by 4
    for (int i = tid; i < total4; i += 256) gv[i] = sv[i];
}

// Patch: fold phase-A overflow edges into cnt/slots (empty in normal runs).
__global__ __launch_bounds__(256) void k_patch(const int2* __restrict__ ovfA,
                                               const int* __restrict__ ovfAcnt,
                                               int* __restrict__ cnt,
                                               int* __restrict__ slots,
                                               int2* __restrict__ ovf2,
                                               int* __restrict__ ovf2cnt, int N) {
    int n = *ovfAcnt; n = n < OVF_MAX ? n : OVF_MAX;
    for (int i = blockIdx.x * 256 + threadIdx.x; i < n; i += gridDim.x * 256) {
        int2 p = ovfA[i];
        int pos = atomicAdd(&cnt[p.x], 1);
        if (pos < CAP) {
            slots[(long)p.x * CAP + pos] = p.y;
        } else {
            int op = atomicAdd(ovf2cnt, 1);
            if (op < OVF_MAX) ovf2[op] = p;
        }
    }
}

// MFMA GEMM: G[row,:C] = bf16( rsqrt(cnt[row]+1) * (X[row,:128] @ W[:128,:C]) )
template<int CT>
__global__ __launch_bounds__(256) void k_gemm(const void* __restrict__ Xp, int x_follows_flag,
                                              const void* __restrict__ Wp,
                                              const int* __restrict__ cnt,
                                              __hip_bfloat16* __restrict__ G,
                                              const int* __restrict__ flags, int N) {
    constexpr int C = CT * 16;
    __shared__ __align__(16) short Wt[C * 136];   // W^T bf16, pad 128->136
    const bool f32m = flags[0] != 0;
    const bool xf32 = (x_follows_flag != 0) && f32m;
    const int tid = threadIdx.x;
    for (int i = tid; i < 128 * C; i += 256) {
        int k = i / C, n = i % C;
        float wv = f32m ? ((const float*)Wp)[(long)k * C + n]
                        : bf2f(((const __hip_bfloat16*)Wp)[(long)k * C + n]);
        Wt[n * 136 + k] = (short)f2bfu(wv);
    }
    __syncthreads();
    const int w = tid >> 6, lane = tid & 63;
    const int m = lane & 15, quad = lane >> 4;
    const int rowA = blockIdx.x * 64 + w * 16 + m;
    const int rowc = rowA < N ? rowA : N - 1;
    s16x8 afr[4];
#pragma unroll
    for (int kc = 0; kc < 4; ++kc) {
        const int k0 = kc * 32 + quad * 8;
        if (!xf32) {
            afr[kc] = *(const s16x8*)((const __hip_bfloat16*)Xp + (long)rowc * 128 + k0);
        } else {
            const float* p = (const float*)Xp + (long)rowc * 128 + k0;
            s16x8 t;
#pragma unroll
            for (int j = 0; j < 8; ++j) t[j] = (short)f2bfu(p[j]);
            afr[kc] = t;
        }
    }
    const int rbase = blockIdx.x * 64 + w * 16 + quad * 4;
    float dv[4];
#pragma unroll
    for (int r = 0; r < 4; ++r) {
        int rr = min(rbase + r, N - 1);
        dv[r] = rsqrtf((float)(cnt[rr] + 1));
    }
#pragma unroll
    for (int ct = 0; ct < CT; ++ct) {
        f32x4 acc = {0.f, 0.f, 0.f, 0.f};
#pragma unroll
        for (int kc = 0; kc < 4; ++kc) {
            s16x8 bfr = *(const s16x8*)&Wt[(ct * 16 + m) * 136 + kc * 32 + quad * 8];
            acc = __builtin_amdgcn_mfma_f32_16x16x32_bf16(afr[kc], bfr, acc, 0, 0, 0);
        }
#pragma unroll
        for (int r = 0; r < 4; ++r) {
            int rr = rbase + r;
            if (rr < N) G[(long)rr * C + ct * 16 + m] = __float2bfloat16(dv[r] * acc[r]);
        }
    }
}

// LDS-free gather. OUT[d,:F] = act( rsqrt(cnt[d]+1) * (G[d,:] + sum_s G[s,:]) + bias )
template<int F, int LAYER1>
__global__ __launch_bounds__(256) void k_gather(const __hip_bfloat16* __restrict__ G,
                                                const int* __restrict__ cnt,
                                                const int* __restrict__ slots,
                                                const int2* __restrict__ ovf2,
                                                const int* __restrict__ ovf2cnt,
                                                const void* __restrict__ bias,
                                                void* __restrict__ outp,
                                                const int* __restrict__ flags, int N) {
    constexpr int L = F / 8;
    constexpr int NODES = 256 / L;
    const int tid = threadIdx.x;
    const int grp = tid / L, lane = tid % L;
    const int node = blockIdx.x * NODES + grp;
    if (node >= N) return;
    const int cd = cnt[node];
    const float wself = rsqrtf((float)(cd + 1));
    const int m = cd < CAP ? cd : CAP;
    const int* sl = slots + (long)node * CAP;
    float acc[8] = {0, 0, 0, 0, 0, 0, 0, 0};
    acc_add(acc, ((const uint4*)(G + (long)node * F))[lane]);   // self loop
    int i = 0;
    for (; i + 3 < m; i += 4) {
        int s0 = sl[i], s1 = sl[i + 1], s2 = sl[i + 2], s3 = sl[i + 3];
        uint4 v0 = ((const uint4*)(G + (long)s0 * F))[lane];
        uint4 v1 = ((const uint4*)(G + (long)s1 * F))[lane];
        uint4 v2 = ((const uint4*)(G + (long)s2 * F))[lane];
        uint4 v3 = ((const uint4*)(G + (long)s3 * F))[lane];
        acc_add(acc, v0); acc_add(acc, v1); acc_add(acc, v2); acc_add(acc, v3);
    }
    for (; i < m; ++i)
        acc_add(acc, ((const uint4*)(G + (long)sl[i] * F))[lane]);
    if (cd > CAP) {  // rare overflow
        int oc = *ovf2cnt; oc = oc < OVF_MAX ? oc : OVF_MAX;
        for (int j = 0; j < oc; ++j)
            if (ovf2[j].x == node)
                acc_add(acc, ((const uint4*)(G + (long)ovf2[j].y * F))[lane]);
    }
    const bool f32m = flags[0] != 0;
    const int c0 = lane * 8;
    float bv[8];
    if (f32m) {
        const float4* bp = (const float4*)((const float*)bias + c0);
        float4 b0 = bp[0], b1 = bp[1];
        bv[0] = b0.x; bv[1] = b0.y; bv[2] = b0.z; bv[3] = b0.w;
        bv[4] = b1.x; bv[5] = b1.y; bv[6] = b1.z; bv[7] = b1.w;
    } else {
        uint4 b = *(const uint4*)((const __hip_bfloat16*)bias + c0);
        bv[0] = lo2f(b.x); bv[1] = hi2f(b.x); bv[2] = lo2f(b.y); bv[3] = hi2f(b.y);
        bv[4] = lo2f(b.z); bv[5] = hi2f(b.z); bv[6] = lo2f(b.w); bv[7] = hi2f(b.w);
    }
    float o[8];
#pragma unroll
    for (int c = 0; c < 8; ++c) {
        float v = wself * acc[c] + bv[c];
        o[c] = (LAYER1 && v < 0.f) ? 0.f : v;
    }
    if (LAYER1 || !f32m) {
        uint4 pv = { pack2(o[0], o[1]), pack2(o[2], o[3]), pack2(o[4], o[5]), pack2(o[6], o[7]) };
        ((uint4*)outp)[(long)node * L + lane] = pv;
    } else {
        float4* op = (float4*)((float*)outp + (long)node * F + c0);
        op[0] = make_float4(o[0], o[1], o[2], o[3]);
        op[1] = make_float4(o[4], o[5], o[6], o[7]);
    }
}

extern "C" void kernel_launch(void* const* d_in, const int* in_sizes, int n_in,
                              void* d_out, int out_size, void* d_ws, size_t ws_size,
                              hipStream_t stream) {
    const void* x  = d_in[0];
    const int*  ei = (const int*)d_in[1];
    const void* W1 = d_in[2];
    const void* b1 = d_in[3];
    const void* W2 = d_in[4];
    const void* b2 = d_in[5];

    const int N = in_sizes[0] / FIN;   // 50000
    const int E = in_sizes[1] / 2;     // 800000
    const int nbuk = (N + NPB - 1) / NPB;   // 511 for N=50000 (<=1024 supported)

    // ws layout (bytes), peak ~37.1MB (ws >= 39.2MB established R2):
    //   flags @0
    //   gcur  @4096   (1024 ints; [1024]=ovfAcnt, [1025]=ovf2cnt)
    //   cnt   @65536  (4N)
    //   ovfA  @524288  (512KB int2)
    //   ovf2  @1048576 (512KB int2)
    //   slots @2097152 (N*CAP*4 = 9.6MB)
    //   g     @11730944 (12.8MB bf16; g2 overlays after gather1)
    //   pairs @24530944 (nbuk*BCAP*8 = 12.56MB; h1 overlays after binB/patch)
    char* ws = (char*)d_ws;
    int*   flags   = (int*)ws;
    int*   gcur    = (int*)(ws + 4096);
    int*   ovfAcnt = gcur + 1024;
    int*   ovf2cnt = gcur + 1025;
    int*   cnt     = (int*)(ws + 65536);
    int2*  ovfA    = (int2*)(ws + 524288);
    int2*  ovf2    = (int2*)(ws + 1048576);
    int*   slots   = (int*)(ws + 2097152);
    __hip_bfloat16* g  = (__hip_bfloat16*)(ws + 11730944);
    __hip_bfloat16* g2 = g;                                     // overlays g
    int2*  pairs   = (int2*)(ws + 24530944);
    __hip_bfloat16* h1 = (__hip_bfloat16*)(ws + 24530944);      // overlays pairs

    const int GB = (N + 63) / 64;
    const int AB = (E + 4095) / 4096;

    k_detect<<<1, 256, 0, stream>>>((const unsigned*)x, ei, E, flags, gcur);
    k_binA<<<AB, 256, 0, stream>>>(ei, E, N, nbuk, gcur, pairs, ovfA, ovfAcnt, flags);
    k_binB<<<nbuk, 256, 0, stream>>>(gcur, pairs, cnt, slots, ovf2, ovf2cnt, N);
    k_patch<<<32, 256, 0, stream>>>(ovfA, ovfAcnt, cnt, slots, ovf2, ovf2cnt, N);
    // layer 1
    k_gemm<8><<<GB, 256, 0, stream>>>(x, 1, W1, cnt, g, flags, N);
    k_gather<128, 1><<<(N + 15) / 16, 256, 0, stream>>>(g, cnt, slots, ovf2, ovf2cnt, b1, h1, flags, N);
    // layer 2
    k_gemm<4><<<GB, 256, 0, stream>>>(h1, 0, W2, cnt, g2, flags, N);
    k_gather<64, 0><<<(N + 31) / 32, 256, 0, stream>>>(g2, cnt, slots, ovf2, ovf2cnt, b2, d_out, flags, N);
}